// Round 4
// baseline (349.322 us; speedup 1.0000x reference)
//
#include <hip/hip_runtime.h>
#include <math.h>

#define S_TOK 65536
#define H_DIM 768
#define T_TYPES 6
#define K_TOP 3
#define WIN 15
#define NBLK1 2048
#define ROWS_PER_BLK (S_TOK / NBLK1)         // 32
#define NRANGES NBLK1                        // 2048 (one per block)
#define POOL_CHUNKS 16
#define BLK_PER_CHUNK (NBLK1 / POOL_CHUNKS)  // 128

// ---------------------------------------------------------------------------
// top-3 insert with jnp tie-breaking (equal value -> lower index wins)
// ---------------------------------------------------------------------------
__device__ __forceinline__ void top3_insert(float v, int i,
    float& v0, float& v1, float& v2, int& i0, int& i1, int& i2)
{
    if (v > v0 || (v == v0 && i < i0)) {
        v2 = v1; i2 = i1; v1 = v0; i1 = i0; v0 = v; i0 = i;
    } else if (v > v1 || (v == v1 && i < i1)) {
        v2 = v1; i2 = i1; v1 = v; i1 = i;
    } else if (v > v2 || (v == v2 && i < i2)) {
        v2 = v; i2 = i;
    }
}

__device__ __forceinline__ void merge_state(
    float& M, float& se, float& v0, float& v1, float& v2,
    int& i0, int& i1, int& i2,
    float Mb, float seb, float w0, float w1, float w2,
    int j0, int j1, int j2)
{
    const float Mn = fmaxf(M, Mb);
    se = se * expf(M - Mn) + seb * expf(Mb - Mn);
    M = Mn;
    top3_insert(w0, j0, v0, v1, v2, i0, i1, i2);
    top3_insert(w1, j1, v0, v1, v2, i0, i1, i2);
    top3_insert(w2, j2, v0, v1, v2, i0, i1, i2);
}

// ---------------------------------------------------------------------------
// Kernel 1: single HBM pass over token_embeds (192 MiB).
// Block = 4 waves, owns 32 contiguous rows; ALL 4 waves read the same rows
// (repeat reads served by L1/L2, HBM traffic unchanged). Wave w computes
// only 3 of the 12 outputs:
//   w=0: start types 0-2   w=1: start types 3-5   (online softmax + top3)
//   w=2: end   types 0-2   w=3: end   types 3-5   (stored to endS[T][S])
// => 36 weight VGPRs/lane instead of 144 -> 4 waves/SIMD occupancy.
// Packed-halving butterfly: 7 shuffles/row for 3 accumulators.
// Wave 3 additionally accumulates the pooled column sums in registers and
// writes them directly (no LDS, no __syncthreads).
// ---------------------------------------------------------------------------
__global__ __launch_bounds__(256, 4) void k_scores(
    const float* __restrict__ emb,
    const float* __restrict__ Wstart, const float* __restrict__ bstart,
    const float* __restrict__ Wend,   const float* __restrict__ bend,
    float* __restrict__ endS,         // [T_TYPES][S_TOK]
    float* __restrict__ partials,     // [NRANGES][T_TYPES][8]
    float* __restrict__ pooledPart)   // [NBLK1][H_DIM]
{
    const int lane = threadIdx.x & 63;
    const int wib  = threadIdx.x >> 6;          // 0..3
    const bool isStartW = (wib < 2);
    const int  tbase = (wib & 1) * 3;           // local type base
    const bool b5 = (lane & 32) != 0;
    const bool b4 = (lane & 16) != 0;
    const int  sem = b4 ? 2 : (b5 ? 1 : 0);
    const bool desig = (lane == 0) || (lane == 16) || (lane == 32);

    // 36 weight regs: this wave's 3 output columns at this lane's 12 h's
    const float* Wmat = isStartW ? Wstart : Wend;
    float wG[3][4][3];
#pragma unroll
    for (int j = 0; j < 3; ++j)
#pragma unroll
        for (int c = 0; c < 4; ++c) {
            const int h = 4 * (lane + 64 * j) + c;
#pragma unroll
            for (int u = 0; u < 3; ++u)
                wG[j][c][u] = Wmat[h * T_TYPES + tbase + u];
        }

    float myBias = 0.0f;
    if (desig) myBias = (isStartW ? bstart : bend)[tbase + sem];

    // pooled column partials (used by wave 3 only; cheap everywhere)
    float4 pool[3];
#pragma unroll
    for (int j = 0; j < 3; ++j) pool[j] = make_float4(0.f, 0.f, 0.f, 0.f);

    // online softmax + top3 state (meaningful on start waves' desig lanes)
    float M  = -3.402823466e38f, se = 0.0f;
    float v0 = -3.402823466e38f, v1 = v0, v2 = v0;
    int   i0 = -1, i1 = -1, i2 = -1;

    const int r0 = blockIdx.x * ROWS_PER_BLK;
    const float4* rowp = (const float4*)emb + (size_t)r0 * (H_DIM / 4);
    float4 c0 = rowp[lane], c1 = rowp[lane + 64], c2 = rowp[lane + 128];

    for (int r = r0; r < r0 + ROWS_PER_BLK; ++r) {
        const float4* nextp = rowp + ((r + 1 < S_TOK) ? (H_DIM / 4) : 0);
        float4 n0 = nextp[lane], n1 = nextp[lane + 64], n2 = nextp[lane + 128];

        float a0 = 0.0f, a1 = 0.0f, a2 = 0.0f;
        const float4 ee[3] = {c0, c1, c2};
#pragma unroll
        for (int j = 0; j < 3; ++j) {
            const float ev[4] = {ee[j].x, ee[j].y, ee[j].z, ee[j].w};
            pool[j].x += ev[0]; pool[j].y += ev[1];
            pool[j].z += ev[2]; pool[j].w += ev[3];
#pragma unroll
            for (int c = 0; c < 4; ++c) {
                const float v = ev[c];
                a0 = fmaf(v, wG[j][c][0], a0);
                a1 = fmaf(v, wG[j][c][1], a1);
                a2 = fmaf(v, wG[j][c][2], a2);
            }
        }

        // packed-halving butterfly: 7 shuffles
        // step 1 (mask 32): b5=0 keeps a0 (sem0), b5=1 keeps a1 (sem1)
        float snd = b5 ? a0 : a1;
        float kp  = b5 ? a1 : a0;
        float x0 = kp + __shfl_xor(snd, 32, 64);
        float x1 = a2 + __shfl_xor(a2, 32, 64);
        // step 2 (mask 16): b4=0 keeps x0 (sem b5), b4=1 keeps x1 (sem2)
        snd = b4 ? x0 : x1;
        kp  = b4 ? x1 : x0;
        float y = kp + __shfl_xor(snd, 16, 64);
        // steps 3-6: plain
        y += __shfl_xor(y, 8, 64);
        y += __shfl_xor(y, 4, 64);
        y += __shfl_xor(y, 2, 64);
        y += __shfl_xor(y, 1, 64);

        const float v = y + myBias;

        if (isStartW) {
            if (desig) {
                if (v > M) {
                    se = se * expf(M - v) + 1.0f;
                    v2 = v1; i2 = i1; v1 = v0; i1 = i0; v0 = v; i0 = r;
                    M = v;
                } else {
                    se += expf(v - M);
                    if (v > v2 || (v == v2 && r < i2)) {
                        if (v > v1 || (v == v1 && r < i1)) {
                            v2 = v1; i2 = i1; v1 = v; i1 = r;
                        } else { v2 = v; i2 = r; }
                    }
                }
            }
        } else {
            if (desig) endS[(size_t)(tbase + sem) * S_TOK + r] = v;
        }

        c0 = n0; c1 = n1; c2 = n2; rowp = nextp;
    }

    if (isStartW && desig) {
        float* p = partials + ((size_t)blockIdx.x * T_TYPES + (tbase + sem)) * 8;
        p[0] = M;  p[1] = se; p[2] = v0; p[3] = v1; p[4] = v2;
        p[5] = __int_as_float(i0);
        p[6] = __int_as_float(i1);
        p[7] = __int_as_float(i2);
    }

    if (wib == 3) {
        float4* pp4 = (float4*)(pooledPart + (size_t)blockIdx.x * H_DIM);
        pp4[lane]       = pool[0];
        pp4[lane + 64]  = pool[1];
        pp4[lane + 128] = pool[2];
    }
}

// ---------------------------------------------------------------------------
// Kernel 2 (22 blocks x 1024):
//   blocks 0..5   : combine 2048 per-range (M,se,top3) partials of type b
//   blocks 6..21  : pooled chunk reduce (128 block-partials) + the chunk's
//                   W1 GEMV partial z[c][64]
// ---------------------------------------------------------------------------
__global__ __launch_bounds__(1024) void k_mid(
    const float* __restrict__ partials,
    const float* __restrict__ pooledPart,
    const float* __restrict__ W1,
    float* __restrict__ zpart,          // [POOL_CHUNKS][64]
    float* __restrict__ res)            // [T_TYPES][8]
{
    const int b = blockIdx.x;
    const int tid = threadIdx.x;

    if (b >= T_TYPES) {
        const int c = b - T_TYPES;
        __shared__ float pl[H_DIM];
        if (tid < H_DIM) {
            const float* base = pooledPart + (size_t)c * BLK_PER_CHUNK * H_DIM + tid;
            float s[8] = {0, 0, 0, 0, 0, 0, 0, 0};
            for (int i = 0; i < BLK_PER_CHUNK; i += 8) {
#pragma unroll
                for (int u = 0; u < 8; ++u)
                    s[u] += base[(size_t)(i + u) * H_DIM];
            }
            pl[tid] = ((s[0] + s[1]) + (s[2] + s[3])) +
                      ((s[4] + s[5]) + (s[6] + s[7]));
        }
        __syncthreads();
        // z[c][o] = sum_h pl[h] * W1[h][o], 16 segments x 48 h each
        const int o = tid & 63, seg = tid >> 6;
        float z = 0.0f;
        const int h0 = seg * 48;
        for (int i = 0; i < 48; ++i)
            z = fmaf(pl[h0 + i], W1[(size_t)(h0 + i) * 64 + o], z);
        __shared__ float zred[16][64];
        zred[seg][o] = z;
        __syncthreads();
        if (tid < 64) {
            float s = 0.0f;
#pragma unroll
            for (int g = 0; g < 16; ++g) s += zred[g][tid];
            zpart[c * 64 + tid] = s;
        }
        return;
    }

    float M, se, v0, v1, v2; int i0, i1, i2;
    {
        const float* p = partials + ((size_t)tid * T_TYPES + b) * 8;
        M = p[0]; se = p[1]; v0 = p[2]; v1 = p[3]; v2 = p[4];
        i0 = __float_as_int(p[5]); i1 = __float_as_int(p[6]); i2 = __float_as_int(p[7]);
    }
    {
        const float* p = partials + ((size_t)(tid + 1024) * T_TYPES + b) * 8;
        merge_state(M, se, v0, v1, v2, i0, i1, i2,
                    p[0], p[1], p[2], p[3], p[4],
                    __float_as_int(p[5]), __float_as_int(p[6]), __float_as_int(p[7]));
    }

#pragma unroll
    for (int msk = 1; msk < 64; msk <<= 1) {
        const float Mb  = __shfl_xor(M,  msk, 64);
        const float seb = __shfl_xor(se, msk, 64);
        const float w0  = __shfl_xor(v0, msk, 64);
        const float w1  = __shfl_xor(v1, msk, 64);
        const float w2  = __shfl_xor(v2, msk, 64);
        const int   j0  = __shfl_xor(i0, msk, 64);
        const int   j1  = __shfl_xor(i1, msk, 64);
        const int   j2  = __shfl_xor(i2, msk, 64);
        merge_state(M, se, v0, v1, v2, i0, i1, i2, Mb, seb, w0, w1, w2, j0, j1, j2);
    }

    __shared__ float sm[16][8];
    if ((tid & 63) == 0) {
        const int w = tid >> 6;
        sm[w][0] = M;  sm[w][1] = se;
        sm[w][2] = v0; sm[w][3] = v1; sm[w][4] = v2;
        sm[w][5] = __int_as_float(i0);
        sm[w][6] = __int_as_float(i1);
        sm[w][7] = __int_as_float(i2);
    }
    __syncthreads();
    if (tid == 0) {
        for (int w = 1; w < 16; ++w) {
            merge_state(M, se, v0, v1, v2, i0, i1, i2,
                        sm[w][0], sm[w][1], sm[w][2], sm[w][3], sm[w][4],
                        __float_as_int(sm[w][5]), __float_as_int(sm[w][6]),
                        __float_as_int(sm[w][7]));
        }
        float* r = res + b * 8;
        r[0] = v0; r[1] = v1; r[2] = v2;
        r[3] = __int_as_float(i0);
        r[4] = __int_as_float(i1);
        r[5] = __int_as_float(i2);
        r[6] = M; r[7] = se;
    }
}

// ---------------------------------------------------------------------------
// Kernel 3: tiny epilogue. z-sum -> GELU -> W2 -> sigmoid; softmax top-vals
// from (M,SE); 15-wide window argmax; write all 72 f32 outputs.
// ---------------------------------------------------------------------------
__global__ __launch_bounds__(256) void k_final(
    const float* __restrict__ zpart,
    const float* __restrict__ b1,
    const float* __restrict__ W2, const float* __restrict__ b2,
    const float* __restrict__ endS, const float* __restrict__ res,
    float* __restrict__ out)
{
    const int tid = threadIdx.x;
    __shared__ float hdn[64];
    if (tid < 64) {
        float zs = 0.0f;
#pragma unroll
        for (int c = 0; c < POOL_CHUNKS; ++c) zs += zpart[c * 64 + tid];
        const float z = zs * (1.0f / (float)S_TOK) + b1[tid];
        hdn[tid] = 0.5f * z * (1.0f + erff(z * 0.7071067811865475f));
    }
    __syncthreads();

    __shared__ float tconf[T_TYPES];
    if (tid < T_TYPES) {
        float z = b2[tid];
        for (int i = 0; i < 64; ++i) z = fmaf(hdn[i], W2[i * T_TYPES + tid], z);
        tconf[tid] = 1.0f / (1.0f + expf(-z));
    }
    __syncthreads();

    if (tid < T_TYPES * K_TOP) {
        const int t = tid / K_TOP;
        const int k = tid % K_TOP;
        const float* r = res + t * 8;
        const float vraw = r[k];
        const int   idx  = __float_as_int(r[3 + k]);
        const float M    = r[6];
        const float SE   = r[7];
        const float prob = expf(vraw - M) / SE;

        const float* ecol = endS + (size_t)t * S_TOK;
        float best = -3.402823466e38f;
        int   boff = 0;
#pragma unroll
        for (int w = 0; w < WIN; ++w) {
            const int pos = idx + w;
            if (pos < S_TOK) {
                const float ev = ecol[pos];
                if (ev > best) { best = ev; boff = w; }
            }
        }
        const float tc = tconf[t];
        const bool valid = (tc >= 0.3f) && (prob >= 0.15f);
        out[tid]      = valid ? prob * tc : 0.0f;
        out[18 + tid] = (float)idx;
        out[36 + tid] = (float)(idx + boff + 1);
        out[54 + tid] = valid ? 1.0f : 0.0f;
    }
}

extern "C" void kernel_launch(void* const* d_in, const int* in_sizes, int n_in,
                              void* d_out, int out_size, void* d_ws, size_t ws_size,
                              hipStream_t stream)
{
    const float* emb    = (const float*)d_in[0];
    const float* Wstart = (const float*)d_in[1];
    const float* bstart = (const float*)d_in[2];
    const float* Wend   = (const float*)d_in[3];
    const float* bend   = (const float*)d_in[4];
    const float* W1     = (const float*)d_in[5];
    const float* b1     = (const float*)d_in[6];
    const float* W2     = (const float*)d_in[7];
    const float* b2     = (const float*)d_in[8];
    float* out = (float*)d_out;

    // workspace layout (floats)
    float* ws       = (float*)d_ws;
    float* endS     = ws;                                          // 6*65536
    float* partials = endS + (size_t)T_TYPES * S_TOK;              // 2048*6*8
    float* pp       = partials + (size_t)NRANGES * T_TYPES * 8;    // 2048*768
    float* zpart    = pp + (size_t)NBLK1 * H_DIM;                  // 16*64
    float* res      = zpart + (size_t)POOL_CHUNKS * 64;            // 6*8

    k_scores<<<NBLK1, 256, 0, stream>>>(emb, Wstart, bstart, Wend, bend,
                                        endS, partials, pp);
    k_mid<<<T_TYPES + POOL_CHUNKS, 1024, 0, stream>>>(partials, pp, W1, zpart, res);
    k_final<<<1, 256, 0, stream>>>(zpart, b1, W2, b2, endS, res, out);
}